// Round 4
// baseline (1026.202 us; speedup 1.0000x reference)
//
#include <hip/hip_runtime.h>
#include <cstdint>

typedef __bf16 bf16;
typedef __attribute__((ext_vector_type(8))) __bf16 bf16x8;
typedef __attribute__((ext_vector_type(4))) __bf16 bf16x4;
typedef __attribute__((ext_vector_type(4))) float f32x4;
typedef __attribute__((ext_vector_type(2))) float f32x2;

static __device__ __forceinline__ float elu1(float x) {
    return x > 0.f ? x : (__expf(x) - 1.f);
}

// global -> LDS async copy, 16 B per lane. LDS dest must be wave-uniform
// base + lane*16 (pass per-lane ptr; lane 0's value is the base).
static __device__ __forceinline__ void gl_lds16(const void* gp, void* lp) {
    __builtin_amdgcn_global_load_lds(
        (const __attribute__((address_space(1))) void*)(uintptr_t)gp,
        (__attribute__((address_space(3))) void*)(uint32_t)(uintptr_t)lp,
        16, 0, 0);
}

// ---------------------------------------------------------------------------
// Weight conversion: f32 -> bf16, all weights concatenated into ws, with
// phi1_w1 row-padded 514 -> 576 (zeros) so K-steps stay 64-wide.
// ---------------------------------------------------------------------------
struct CvtArgs {
    const float* src[13];
    int rows[13];
    int scols[13];
    int dcols[13];
    int total;
};

__global__ void cvt_k(CvtArgs a, bf16* __restrict__ dst) {
    int idx = blockIdx.x * 256 + threadIdx.x;
    if (idx >= a.total) return;
    int rem = idx;
#pragma unroll 1
    for (int s = 0; s < 13; ++s) {
        int sz = a.rows[s] * a.dcols[s];
        if (rem < sz) {
            int r = rem / a.dcols[s];
            int c = rem - r * a.dcols[s];
            float v = (c < a.scols[s]) ? a.src[s][(long)r * a.scols[s] + c] : 0.f;
            dst[idx] = (bf16)v;
            return;
        }
        rem -= sz;
    }
}

// encA (65536 x 514 f32) -> Apad (65536 x 576 bf16, zero-padded).
// One 8-col chunk per thread, vectorized f32x2 loads (rows are 8B-aligned).
__global__ void cvtA_k(const float* __restrict__ src, bf16* __restrict__ dst) {
    const int idx = blockIdx.x * 256 + threadIdx.x;
    const int r = idx / 72;            // 72 = 576/8 chunks per row
    const int c8 = (idx - r * 72) * 8;
    const float* sp = src + (long)r * 514 + c8;
    bf16x8 t;
    if (c8 + 8 <= 514) {
        f32x2 p0 = *(const f32x2*)(sp + 0);
        f32x2 p1 = *(const f32x2*)(sp + 2);
        f32x2 p2 = *(const f32x2*)(sp + 4);
        f32x2 p3 = *(const f32x2*)(sp + 6);
        t[0] = (bf16)p0.x; t[1] = (bf16)p0.y; t[2] = (bf16)p1.x; t[3] = (bf16)p1.y;
        t[4] = (bf16)p2.x; t[5] = (bf16)p2.y; t[6] = (bf16)p3.x; t[7] = (bf16)p3.y;
    } else {
#pragma unroll
        for (int e = 0; e < 8; ++e) {
            const int col = c8 + e;
            t[e] = (bf16)(col < 514 ? sp[e] : 0.f);
        }
    }
    *(bf16x8*)(dst + (long)r * 576 + c8) = t;
}

// ---------------------------------------------------------------------------
// Tiled GEMM (m97 structure): C = act(A @ W^T + bias)
// 128x128 block tile, BK=64, 256 threads = 4 waves, each wave 64x64
// (4x4 grid of 16x16x32 MFMA). LDS staged via global_load_lds (bf16
// operands) or VALU compose + ds_write (f32 / fused alt_val A).
// Single-buffer 2-phase loop (sync, stage, sync, compute) — measured
// fastest; BOTH double-buffer variants regressed (r2: runtime LDS index
// forces vmcnt(0) before ds_reads; r3: true overlap tripled HBM fetch by
// thrashing the L2/L3 reuse of re-read A-panels).
// Latency hiding comes from occupancy instead: __launch_bounds__(256,4)
// = 4 blocks/CU (128 KB LDS, VGPR<=128 fits measured 68-116), doubling
// the cross-block stage/compute overlap vs the previous (256,2).
// Non-bf16 A modes register-prefetch the next K-step's raw A sources
// after the second barrier so their HBM latency hides under the MFMAs.
// Swizzled LDS layout: 16B chunk p of row m stored at slot (p+m)&7.
// ---------------------------------------------------------------------------
struct GemmArgs {
    const float* Af;
    const bf16*  Ab;
    long lda;
    const float* enc;    // ALT mode
    const float* km;     // ALT mode
    const bf16*  key1;   // ALT mode
    const bf16*  W;
    long ldw;
    const float* bias;
    bf16*  Cb;
    float* Cf;
    long ldc;
    int nK;              // number of 64-wide K-steps
    int klim;            // valid A cols (F32U bounds)
};

enum { AM_F32 = 0, AM_F32U = 1, AM_BF16 = 2, AM_ALT = 3 };
enum { ACT_NONE = 0, ACT_ELU = 1, ACT_ELU2 = 2 };

template <int AMODE, int ACT, bool OUTB>
__global__ __launch_bounds__(256, 4) void gemm_t(GemmArgs g) {
    __shared__ bf16 As[128 * 64];
    __shared__ bf16 Bs[128 * 64];

    const int tid  = threadIdx.x;
    const int wave = tid >> 6;
    const int lane = tid & 63;
    const int ln   = lane & 15;
    const int quad = lane >> 4;

    const long m0 = (long)blockIdx.x * 128;
    const long n0 = (long)blockIdx.y * 128;
    const int  wm = (wave & 1) * 64;
    const int  wn = (wave >> 1) * 64;

    f32x4 acc[4][4] = {};

    // per-thread A-chunk metadata for VALU-composed modes (loop-invariant)
    int cm[4], cs[4];
    long ar[4];
    if constexpr (AMODE != AM_BF16) {
#pragma unroll
        for (int r = 0; r < 4; ++r) {
            const int c = r * 256 + tid;
            cm[r] = c >> 3;
            cs[r] = c & 7;
            ar[r] = m0 + cm[r];
        }
    }

    // prefetch registers (only the set for the active mode is live)
    f32x4 pf[4][2];                     // AM_F32
    float pu[4][8];                     // AM_F32U
    f32x4 pe[4][2], pq[4][2];           // AM_ALT
    bf16x8 px[4];                       // AM_ALT

    auto loadA = [&](int k0) {
#pragma unroll
        for (int r = 0; r < 4; ++r) {
            const int kk = k0 + (((cs[r] - cm[r]) & 7) << 3);
            if constexpr (AMODE == AM_F32) {
                const float* ap = g.Af + ar[r] * g.lda + kk;
                pf[r][0] = *(const f32x4*)ap;
                pf[r][1] = *(const f32x4*)(ap + 4);
            } else if constexpr (AMODE == AM_F32U) {
                const float* ap = g.Af + ar[r] * g.lda;
                if (kk + 8 <= g.klim) {
#pragma unroll
                    for (int e = 0; e < 8; e += 2) {
                        f32x2 p = *(const f32x2*)(ap + kk + e);
                        pu[r][e] = p.x;
                        pu[r][e + 1] = p.y;
                    }
                } else {
#pragma unroll
                    for (int e = 0; e < 8; ++e) {
                        const int col = kk + e;
                        pu[r][e] = col < g.klim ? ap[col] : 0.f;
                    }
                }
            } else if constexpr (AMODE == AM_ALT) {
                const float* ep = g.enc + ar[r] * 512 + kk;
                const float* mp = g.km + (ar[r] >> 4) * 512 + kk;
                pe[r][0] = *(const f32x4*)ep;
                pe[r][1] = *(const f32x4*)(ep + 4);
                pq[r][0] = *(const f32x4*)mp;
                pq[r][1] = *(const f32x4*)(mp + 4);
                px[r] = *(const bf16x8*)(g.key1 + ar[r] * 512 + kk);
            }
        }
    };

    auto writeA = [&]() {
#pragma unroll
        for (int r = 0; r < 4; ++r) {
            bf16x8 t;
            if constexpr (AMODE == AM_F32) {
#pragma unroll
                for (int e = 0; e < 4; ++e) {
                    t[e]     = (bf16)pf[r][0][e];
                    t[e + 4] = (bf16)pf[r][1][e];
                }
            } else if constexpr (AMODE == AM_F32U) {
#pragma unroll
                for (int e = 0; e < 8; ++e) t[e] = (bf16)pu[r][e];
            } else {  // AM_ALT: enc + km[row/16] - key1/16
#pragma unroll
                for (int e = 0; e < 4; ++e) {
                    t[e]     = (bf16)(pe[r][0][e] + pq[r][0][e] - (float)px[r][e] * 0.0625f);
                    t[e + 4] = (bf16)(pe[r][1][e] + pq[r][1][e] - (float)px[r][e + 4] * 0.0625f);
                }
            }
            *(bf16x8*)(&As[cm[r] * 64 + cs[r] * 8]) = t;
        }
    };

    if constexpr (AMODE != AM_BF16) loadA(0);

    for (int ks = 0; ks < g.nK; ++ks) {
        const int k0 = ks * 64;
        __syncthreads();

        // ---- stage A (128 rows x 64 cols = 1024 16B chunks) ----
        if constexpr (AMODE == AM_BF16) {
            const int cbase = wave * 256;
#pragma unroll
            for (int r = 0; r < 4; ++r) {
                const int c = cbase + r * 64 + lane;
                const int m = c >> 3, s = c & 7;
                const int pg = (s - m) & 7;
                gl_lds16(g.Ab + (m0 + m) * g.lda + k0 + pg * 8, &As[c * 8]);
            }
        } else {
            writeA();
        }

        // ---- stage B ----
        {
            const int cbase = wave * 256;
#pragma unroll
            for (int r = 0; r < 4; ++r) {
                const int c = cbase + r * 64 + lane;
                const int n = c >> 3, s = c & 7;
                const int pg = (s - n) & 7;
                gl_lds16(g.W + (n0 + n) * g.ldw + k0 + pg * 8, &Bs[c * 8]);
            }
        }
        __syncthreads();

        // issue next K-step's A-source loads; latency hides under the MFMAs
        if constexpr (AMODE != AM_BF16) {
            if (ks + 1 < g.nK) loadA(k0 + 64);
        }

        // ---- compute: 2 k-subs x 16 MFMA ----
#pragma unroll
        for (int ksub = 0; ksub < 2; ++ksub) {
            bf16x8 av[4], bv[4];
#pragma unroll
            for (int t = 0; t < 4; ++t) {
                const int m = wm + t * 16 + ln;
                const int sa = ((ksub * 4 + quad) + m) & 7;
                av[t] = *(const bf16x8*)(&As[m * 64 + sa * 8]);
                const int n = wn + t * 16 + ln;
                const int sb = ((ksub * 4 + quad) + n) & 7;
                bv[t] = *(const bf16x8*)(&Bs[n * 64 + sb * 8]);
            }
#pragma unroll
            for (int i = 0; i < 4; ++i)
#pragma unroll
                for (int j = 0; j < 4; ++j)
                    acc[i][j] = __builtin_amdgcn_mfma_f32_16x16x32_bf16(
                        av[i], bv[j], acc[i][j], 0, 0, 0);
        }
    }

    // ---- epilogue ----
#pragma unroll
    for (int i = 0; i < 4; ++i) {
        const long rb = m0 + wm + i * 16 + quad * 4;
#pragma unroll
        for (int j = 0; j < 4; ++j) {
            const long n = n0 + wn + j * 16 + ln;
            const float bvs = g.bias[n];
#pragma unroll
            for (int r = 0; r < 4; ++r) {
                float v = acc[i][j][r] + bvs;
                if constexpr (ACT >= ACT_ELU) v = elu1(v);
                if constexpr (ACT == ACT_ELU2) v = elu1(v);
                const long o = (rb + r) * g.ldc + n;
                if constexpr (OUTB) g.Cb[o] = (bf16)v;
                else                g.Cf[o] = v;
            }
        }
    }
}

// ---------------------------------------------------------------------------
// Per-group attention: one wave per (group, head). Computes
// obar[g] = mean_i softmax_j(q_i.k_j/16) @ V  directly (mean folded in).
// ---------------------------------------------------------------------------
__global__ __launch_bounds__(256) void attn_k(const bf16* __restrict__ qkv,
                                              bf16* __restrict__ obar,
                                              int ngroups) {
    const int tid = blockIdx.x * 256 + threadIdx.x;
    const int wv = tid >> 6;
    const int g  = wv >> 1;
    const int h  = wv & 1;
    if (g >= ngroups) return;
    const int lane = threadIdx.x & 63;
    const int i  = lane & 15;
    const int jb = (lane >> 4) << 2;

    const bf16* base  = qkv + (long)g * 16 * 1536;
    const bf16* qrow  = base + (long)i * 1536 + h * 256;
    const bf16* kbase = base + 512 + h * 256;

    float s0 = 0.f, s1 = 0.f, s2 = 0.f, s3 = 0.f;
    for (int kk = 0; kk < 256; kk += 8) {
        bf16x8 qv = *(const bf16x8*)(qrow + kk);
        float qf[8];
#pragma unroll
        for (int e = 0; e < 8; ++e) qf[e] = (float)qv[e];
        bf16x8 k0 = *(const bf16x8*)(kbase + (long)(jb + 0) * 1536 + kk);
        bf16x8 k1 = *(const bf16x8*)(kbase + (long)(jb + 1) * 1536 + kk);
        bf16x8 k2 = *(const bf16x8*)(kbase + (long)(jb + 2) * 1536 + kk);
        bf16x8 k3 = *(const bf16x8*)(kbase + (long)(jb + 3) * 1536 + kk);
#pragma unroll
        for (int e = 0; e < 8; ++e) {
            s0 += qf[e] * (float)k0[e];
            s1 += qf[e] * (float)k1[e];
            s2 += qf[e] * (float)k2[e];
            s3 += qf[e] * (float)k3[e];
        }
    }
    const float sc = 1.f / 16.f;  // 1/sqrt(dh), dh=256
    s0 *= sc; s1 *= sc; s2 *= sc; s3 *= sc;
    float m = fmaxf(fmaxf(s0, s1), fmaxf(s2, s3));
    m = fmaxf(m, __shfl_xor(m, 16));
    m = fmaxf(m, __shfl_xor(m, 32));
    float e0 = __expf(s0 - m), e1 = __expf(s1 - m), e2 = __expf(s2 - m), e3 = __expf(s3 - m);
    float rs = e0 + e1 + e2 + e3;
    rs += __shfl_xor(rs, 16);
    rs += __shfl_xor(rs, 32);
    const float inv = 1.f / (rs * 16.f);  // row-normalize + mean over i
    float cb[4] = {e0 * inv, e1 * inv, e2 * inv, e3 * inv};
#pragma unroll
    for (int msk = 1; msk <= 8; msk <<= 1) {
        cb[0] += __shfl_xor(cb[0], msk);
        cb[1] += __shfl_xor(cb[1], msk);
        cb[2] += __shfl_xor(cb[2], msk);
        cb[3] += __shfl_xor(cb[3], msk);
    }
    float call[16];
#pragma unroll
    for (int j = 0; j < 16; ++j)
        call[j] = __shfl(cb[j & 3], (j >> 2) << 4);

    const int d0 = lane << 2;
    const bf16* vb = base + 1024 + h * 256 + d0;
    float o0 = 0.f, o1 = 0.f, o2 = 0.f, o3 = 0.f;
#pragma unroll
    for (int j = 0; j < 16; ++j) {
        bf16x4 vv = *(const bf16x4*)(vb + (long)j * 1536);
        o0 += call[j] * (float)vv[0];
        o1 += call[j] * (float)vv[1];
        o2 += call[j] * (float)vv[2];
        o3 += call[j] * (float)vv[3];
    }
    bf16x4 ov;
    ov[0] = (bf16)o0; ov[1] = (bf16)o1; ov[2] = (bf16)o2; ov[3] = (bf16)o3;
    *(bf16x4*)(obar + (long)g * 512 + h * 256 + d0) = ov;
}

// q_jt = hg3 @ g_w4^T + g_b4  (4096 x 1)
__global__ void qjt_k(const bf16* __restrict__ hg, const bf16* __restrict__ w,
                      const float* __restrict__ b, float* __restrict__ out) {
    const int m = blockIdx.x * 256 + threadIdx.x;
    const bf16* hp = hg + (long)m * 256;
    float acc = 0.f;
    for (int k = 0; k < 256; k += 8) {
        bf16x8 hv = *(const bf16x8*)(hp + k);
        bf16x8 wv = *(const bf16x8*)(w + k);
#pragma unroll
        for (int e = 0; e < 8; ++e) acc += (float)hv[e] * (float)wv[e];
    }
    out[m] = acc + b[0];
}

// alt_q = hp2 @ phi2_w3^T + phi2_b3  (65536 x 2)
__global__ void altq_k(const bf16* __restrict__ hp, const bf16* __restrict__ w,
                       const float* __restrict__ b, float* __restrict__ out) {
    const int m = blockIdx.x * 256 + threadIdx.x;
    const bf16* hr = hp + (long)m * 256;
    float a0 = 0.f, a1 = 0.f;
    for (int k = 0; k < 256; k += 8) {
        bf16x8 hv = *(const bf16x8*)(hr + k);
        bf16x8 w0 = *(const bf16x8*)(w + k);
        bf16x8 w1 = *(const bf16x8*)(w + 256 + k);
#pragma unroll
        for (int e = 0; e < 8; ++e) {
            float hf = (float)hv[e];
            a0 += hf * (float)w0[e];
            a1 += hf * (float)w1[e];
        }
    }
    out[2 * m]     = a0 + b[0];
    out[2 * m + 1] = a1 + b[1];
}

// ---------------------------------------------------------------------------
extern "C" void kernel_launch(void* const* d_in, const int* in_sizes, int n_in,
                              void* d_out, int out_size, void* d_ws, size_t ws_size,
                              hipStream_t stream) {
    const float* enc    = (const float*)d_in[0];
    const float* encA   = (const float*)d_in[1];
    const float* w_ain  = (const float*)d_in[2];
    const float* b_ain  = (const float*)d_in[3];
    const float* w_aout = (const float*)d_in[4];
    const float* b_aout = (const float*)d_in[5];
    const float* w_p11  = (const float*)d_in[6];
    const float* b_p11  = (const float*)d_in[7];
    const float* w_p12  = (const float*)d_in[8];
    const float* b_p12  = (const float*)d_in[9];
    const float* w_p13  = (const float*)d_in[10];
    const float* b_p13  = (const float*)d_in[11];
    const float* w_p14  = (const float*)d_in[12];
    const float* b_p14  = (const float*)d_in[13];
    const float* w_g1   = (const float*)d_in[14];
    const float* b_g1   = (const float*)d_in[15];
    const float* w_g2   = (const float*)d_in[16];
    const float* b_g2   = (const float*)d_in[17];
    const float* w_g3   = (const float*)d_in[18];
    const float* b_g3   = (const float*)d_in[19];
    const float* w_g4   = (const float*)d_in[20];
    const float* b_g4   = (const float*)d_in[21];
    const float* w_p21  = (const float*)d_in[22];
    const float* b_p21  = (const float*)d_in[23];
    const float* w_p22  = (const float*)d_in[24];
    const float* b_p22  = (const float*)d_in[25];
    const float* w_p23  = (const float*)d_in[26];
    const float* b_p23  = (const float*)d_in[27];
    float* out = (float*)d_out;

    // ---- workspace layout ----
    char* wsc = (char*)d_ws;
    size_t off = 0;
    auto take = [&](size_t bytes) -> char* {
        char* p = wsc + off;
        off += (bytes + 255) & ~(size_t)255;
        return p;
    };

    // weight bf16 region (contiguous, cvt order); p11 padded 514->576
    const long o_ain  = 0;
    const long o_aout = o_ain + 1536L * 512;
    const long o_p11  = o_aout + 512L * 512;
    const long o_p12  = o_p11 + 256L * 576;
    const long o_p13  = o_p12 + 256L * 256;
    const long o_p14  = o_p13 + 256L * 256;
    const long o_g1   = o_p14 + 512L * 256;
    const long o_g2   = o_g1 + 256L * 512;
    const long o_g3   = o_g2 + 256L * 256;
    const long o_g4   = o_g3 + 256L * 256;
    const long o_p21  = o_g4 + 256L;
    const long o_p22  = o_p21 + 256L * 512;
    const long o_p23  = o_p22 + 256L * 256;
    const long wtot   = o_p23 + 2L * 256;

    bf16*  wb  = (bf16*)take((size_t)wtot * 2);
    bf16*  Ha  = (bf16*)take(65536ull * 256 * 2);
    bf16*  Hb  = (bf16*)take(65536ull * 256 * 2);
    bf16*  K1  = (bf16*)take(65536ull * 512 * 2);
    bf16*  OB  = (bf16*)take(4096ull * 512 * 2);
    float* KM  = (float*)take(4096ull * 512 * 4);
    bf16*  HGa = (bf16*)take(4096ull * 256 * 2);
    bf16*  HGb = (bf16*)take(4096ull * 256 * 2);

    // ---- union region: Apad (phi1-1 bf16 A) aliases the QKV chunk buffer
    // (Apad is dead before the first QKV gemm runs) ----
    const size_t apad_b = 65536ull * 576 * 2;
    const size_t avail = ws_size > off ? ws_size - off : 0;
    bool apad_ok = apad_b <= avail;
    auto qkvb = [](int ch) { return (size_t)(65536 / ch) * 1536 * 2; };
    auto need = [&](size_t q) {
        const size_t a = apad_ok ? apad_b : 0;
        return q > a ? q : a;
    };
    int CH = 16;
    if (need(qkvb(2)) <= avail)      CH = 2;
    else if (need(qkvb(4)) <= avail) CH = 4;
    else if (need(qkvb(8)) <= avail) CH = 8;
    else {
        CH = 16;
        if (need(qkvb(16)) > avail) apad_ok = false;
    }
    bf16* U = (bf16*)take(need(qkvb(CH)));
    bf16* Apad = U;
    bf16* QKV  = U;

    // ---- 1. convert weights (+ encA if workspace permits) ----
    CvtArgs ca;
    const float* srcs[13] = {w_ain, w_aout, w_p11, w_p12, w_p13, w_p14,
                             w_g1, w_g2, w_g3, w_g4, w_p21, w_p22, w_p23};
    const int rows_[13]  = {1536, 512, 256, 256, 256, 512, 256, 256, 256, 1, 256, 256, 2};
    const int scols_[13] = {512, 512, 514, 256, 256, 256, 512, 256, 256, 256, 512, 256, 256};
    const int dcols_[13] = {512, 512, 576, 256, 256, 256, 512, 256, 256, 256, 512, 256, 256};
    for (int s = 0; s < 13; ++s) {
        ca.src[s] = srcs[s]; ca.rows[s] = rows_[s];
        ca.scols[s] = scols_[s]; ca.dcols[s] = dcols_[s];
    }
    ca.total = (int)wtot;
    cvt_k<<<dim3((unsigned)((wtot + 255) / 256)), dim3(256), 0, stream>>>(ca, wb);
    if (apad_ok)
        cvtA_k<<<dim3(18432), dim3(256), 0, stream>>>(encA, Apad);

    GemmArgs ga;

    // ---- 2. phi1 chain ----
    if (apad_ok) {
        ga = {}; ga.Ab = Apad; ga.lda = 576;
        ga.W = wb + o_p11; ga.ldw = 576; ga.bias = b_p11;
        ga.Cb = Ha; ga.ldc = 256; ga.nK = 9;
        gemm_t<AM_BF16, ACT_ELU, true><<<dim3(512, 2), 256, 0, stream>>>(ga);
    } else {
        ga = {}; ga.Af = encA; ga.lda = 514; ga.klim = 514;
        ga.W = wb + o_p11; ga.ldw = 576; ga.bias = b_p11;
        ga.Cb = Ha; ga.ldc = 256; ga.nK = 9;
        gemm_t<AM_F32U, ACT_ELU, true><<<dim3(512, 2), 256, 0, stream>>>(ga);
    }

    ga = {}; ga.Ab = Ha; ga.lda = 256; ga.W = wb + o_p12; ga.ldw = 256;
    ga.bias = b_p12; ga.Cb = Hb; ga.ldc = 256; ga.nK = 4;
    gemm_t<AM_BF16, ACT_ELU2, true><<<dim3(512, 2), 256, 0, stream>>>(ga);

    ga = {}; ga.Ab = Hb; ga.lda = 256; ga.W = wb + o_p13; ga.ldw = 256;
    ga.bias = b_p13; ga.Cb = Ha; ga.ldc = 256; ga.nK = 4;
    gemm_t<AM_BF16, ACT_ELU, true><<<dim3(512, 2), 256, 0, stream>>>(ga);

    ga = {}; ga.Ab = Ha; ga.lda = 256; ga.W = wb + o_p14; ga.ldw = 256;
    ga.bias = b_p14; ga.Cb = K1; ga.ldc = 512; ga.nK = 4;
    gemm_t<AM_BF16, ACT_NONE, true><<<dim3(512, 4), 256, 0, stream>>>(ga);

    // ---- 3. chunked qkv + attention ----
    const int Mc = 65536 / CH;
    const int gc = 4096 / CH;
    for (int c = 0; c < CH; ++c) {
        ga = {}; ga.Ab = K1 + (long)c * Mc * 512; ga.lda = 512;
        ga.W = wb + o_ain; ga.ldw = 512; ga.bias = b_ain;
        ga.Cb = QKV; ga.ldc = 1536; ga.nK = 8;
        gemm_t<AM_BF16, ACT_NONE, true>
            <<<dim3(Mc / 128, 12), 256, 0, stream>>>(ga);
        attn_k<<<dim3((gc * 2) / 4), 256, 0, stream>>>(QKV, OB + (long)c * gc * 512, gc);
    }

    // ---- 4. key1_mean = obar @ attn_out_w^T + b (f32 out) ----
    ga = {}; ga.Ab = OB; ga.lda = 512; ga.W = wb + o_aout; ga.ldw = 512;
    ga.bias = b_aout; ga.Cf = KM; ga.ldc = 512; ga.nK = 8;
    gemm_t<AM_BF16, ACT_NONE, false><<<dim3(32, 4), 256, 0, stream>>>(ga);

    // ---- 5. g head ----
    ga = {}; ga.Af = KM; ga.lda = 512; ga.W = wb + o_g1; ga.ldw = 512;
    ga.bias = b_g1; ga.Cb = HGa; ga.ldc = 256; ga.nK = 8;
    gemm_t<AM_F32, ACT_ELU, true><<<dim3(32, 2), 256, 0, stream>>>(ga);

    ga = {}; ga.Ab = HGa; ga.lda = 256; ga.W = wb + o_g2; ga.ldw = 256;
    ga.bias = b_g2; ga.Cb = HGb; ga.ldc = 256; ga.nK = 4;
    gemm_t<AM_BF16, ACT_ELU, true><<<dim3(32, 2), 256, 0, stream>>>(ga);

    ga = {}; ga.Ab = HGb; ga.lda = 256; ga.W = wb + o_g3; ga.ldw = 256;
    ga.bias = b_g3; ga.Cb = HGa; ga.ldc = 256; ga.nK = 4;
    gemm_t<AM_BF16, ACT_ELU, true><<<dim3(32, 2), 256, 0, stream>>>(ga);

    qjt_k<<<dim3(16), 256, 0, stream>>>(HGa, wb + o_g4, b_g4, out);

    // ---- 6. phi2 chain (alt_val fused into A staging) ----
    ga = {}; ga.enc = enc; ga.km = KM; ga.key1 = K1;
    ga.W = wb + o_p21; ga.ldw = 512; ga.bias = b_p21;
    ga.Cb = Ha; ga.ldc = 256; ga.nK = 8;
    gemm_t<AM_ALT, ACT_ELU, true><<<dim3(512, 2), 256, 0, stream>>>(ga);

    ga = {}; ga.Ab = Ha; ga.lda = 256; ga.W = wb + o_p22; ga.ldw = 256;
    ga.bias = b_p22; ga.Cb = Hb; ga.ldc = 256; ga.nK = 4;
    gemm_t<AM_BF16, ACT_ELU, true><<<dim3(512, 2), 256, 0, stream>>>(ga);

    altq_k<<<dim3(256), 256, 0, stream>>>(Hb, wb + o_p23, b_p23, out + 4096);
}

// Round 5
// 796.346 us; speedup vs baseline: 1.2886x; 1.2886x over previous
//
#include <hip/hip_runtime.h>
#include <cstdint>

typedef __bf16 bf16;
typedef __attribute__((ext_vector_type(8))) __bf16 bf16x8;
typedef __attribute__((ext_vector_type(4))) __bf16 bf16x4;
typedef __attribute__((ext_vector_type(4))) float f32x4;
typedef __attribute__((ext_vector_type(2))) float f32x2;

static __device__ __forceinline__ float elu1(float x) {
    return x > 0.f ? x : (__expf(x) - 1.f);
}

// global -> LDS async copy, 16 B per lane. LDS dest must be wave-uniform
// base + lane*16 (pass per-lane ptr; lane 0's value is the base).
static __device__ __forceinline__ void gl_lds16(const void* gp, void* lp) {
    __builtin_amdgcn_global_load_lds(
        (const __attribute__((address_space(1))) void*)(uintptr_t)gp,
        (__attribute__((address_space(3))) void*)(uint32_t)(uintptr_t)lp,
        16, 0, 0);
}

// ---------------------------------------------------------------------------
// Weight conversion: f32 -> bf16, all weights concatenated into ws, with
// phi1_w1 row-padded 514 -> 576 (zeros) so K-steps stay 64-wide.
// ---------------------------------------------------------------------------
struct CvtArgs {
    const float* src[13];
    int rows[13];
    int scols[13];
    int dcols[13];
    int total;
};

__global__ void cvt_k(CvtArgs a, bf16* __restrict__ dst) {
    int idx = blockIdx.x * 256 + threadIdx.x;
    if (idx >= a.total) return;
    int rem = idx;
#pragma unroll 1
    for (int s = 0; s < 13; ++s) {
        int sz = a.rows[s] * a.dcols[s];
        if (rem < sz) {
            int r = rem / a.dcols[s];
            int c = rem - r * a.dcols[s];
            float v = (c < a.scols[s]) ? a.src[s][(long)r * a.scols[s] + c] : 0.f;
            dst[idx] = (bf16)v;
            return;
        }
        rem -= sz;
    }
}

// encA (65536 x 514 f32) -> Apad (65536 x 576 bf16, zero-padded).
// One 8-col chunk per thread, vectorized f32x2 loads (rows are 8B-aligned).
__global__ void cvtA_k(const float* __restrict__ src, bf16* __restrict__ dst) {
    const int idx = blockIdx.x * 256 + threadIdx.x;
    const int r = idx / 72;            // 72 = 576/8 chunks per row
    const int c8 = (idx - r * 72) * 8;
    const float* sp = src + (long)r * 514 + c8;
    bf16x8 t;
    if (c8 + 8 <= 514) {
        f32x2 p0 = *(const f32x2*)(sp + 0);
        f32x2 p1 = *(const f32x2*)(sp + 2);
        f32x2 p2 = *(const f32x2*)(sp + 4);
        f32x2 p3 = *(const f32x2*)(sp + 6);
        t[0] = (bf16)p0.x; t[1] = (bf16)p0.y; t[2] = (bf16)p1.x; t[3] = (bf16)p1.y;
        t[4] = (bf16)p2.x; t[5] = (bf16)p2.y; t[6] = (bf16)p3.x; t[7] = (bf16)p3.y;
    } else {
#pragma unroll
        for (int e = 0; e < 8; ++e) {
            const int col = c8 + e;
            t[e] = (bf16)(col < 514 ? sp[e] : 0.f);
        }
    }
    *(bf16x8*)(dst + (long)r * 576 + c8) = t;
}

// ---------------------------------------------------------------------------
// Tiled GEMM (m97 structure): C = act(A @ W^T + bias)
// 128x128 block tile, BK=64, 256 threads = 4 waves, each wave 64x64
// (4x4 grid of 16x16x32 MFMA). LDS staged via global_load_lds (bf16
// operands) or VALU compose + ds_write (f32 / fused alt_val A).
// Single-buffer 2-phase loop (sync, stage, sync, compute) — measured
// fastest; BOTH double-buffer variants regressed (r2: runtime LDS index
// forces vmcnt(0) before ds_reads; r3: true overlap tripled HBM fetch).
// WPE (waves-per-EU bound): r4 showed __launch_bounds__(256,4) caps
// VGPR at 64 -> catastrophic spills (116-VGPR ALT kernel, 1.3 GB scratch
// traffic). So: bf16-A kernels (68 VGPR natural) use WPE=3 for +50%
// resident blocks; VALU-composed modes (up to 116 VGPR) stay at WPE=2.
// Non-bf16 A modes register-prefetch the next K-step's raw A sources
// after the second barrier so their HBM latency hides under the MFMAs.
// Swizzled LDS layout: 16B chunk p of row m stored at slot (p+m)&7.
// ---------------------------------------------------------------------------
struct GemmArgs {
    const float* Af;
    const bf16*  Ab;
    long lda;
    const float* enc;    // ALT mode
    const float* km;     // ALT mode
    const bf16*  key1;   // ALT mode
    const bf16*  W;
    long ldw;
    const float* bias;
    bf16*  Cb;
    float* Cf;
    long ldc;
    int nK;              // number of 64-wide K-steps
    int klim;            // valid A cols (F32U bounds)
};

enum { AM_F32 = 0, AM_F32U = 1, AM_BF16 = 2, AM_ALT = 3 };
enum { ACT_NONE = 0, ACT_ELU = 1, ACT_ELU2 = 2 };

template <int AMODE, int ACT, bool OUTB, int WPE>
__global__ __launch_bounds__(256, WPE) void gemm_t(GemmArgs g) {
    __shared__ bf16 As[128 * 64];
    __shared__ bf16 Bs[128 * 64];

    const int tid  = threadIdx.x;
    const int wave = tid >> 6;
    const int lane = tid & 63;
    const int ln   = lane & 15;
    const int quad = lane >> 4;

    const long m0 = (long)blockIdx.x * 128;
    const long n0 = (long)blockIdx.y * 128;
    const int  wm = (wave & 1) * 64;
    const int  wn = (wave >> 1) * 64;

    f32x4 acc[4][4] = {};

    // per-thread A-chunk metadata for VALU-composed modes (loop-invariant)
    int cm[4], cs[4];
    long ar[4];
    if constexpr (AMODE != AM_BF16) {
#pragma unroll
        for (int r = 0; r < 4; ++r) {
            const int c = r * 256 + tid;
            cm[r] = c >> 3;
            cs[r] = c & 7;
            ar[r] = m0 + cm[r];
        }
    }

    // prefetch registers (only the set for the active mode is live)
    f32x4 pf[4][2];                     // AM_F32
    float pu[4][8];                     // AM_F32U
    f32x4 pe[4][2], pq[4][2];           // AM_ALT
    bf16x8 px[4];                       // AM_ALT

    auto loadA = [&](int k0) {
#pragma unroll
        for (int r = 0; r < 4; ++r) {
            const int kk = k0 + (((cs[r] - cm[r]) & 7) << 3);
            if constexpr (AMODE == AM_F32) {
                const float* ap = g.Af + ar[r] * g.lda + kk;
                pf[r][0] = *(const f32x4*)ap;
                pf[r][1] = *(const f32x4*)(ap + 4);
            } else if constexpr (AMODE == AM_F32U) {
                const float* ap = g.Af + ar[r] * g.lda;
                if (kk + 8 <= g.klim) {
#pragma unroll
                    for (int e = 0; e < 8; e += 2) {
                        f32x2 p = *(const f32x2*)(ap + kk + e);
                        pu[r][e] = p.x;
                        pu[r][e + 1] = p.y;
                    }
                } else {
#pragma unroll
                    for (int e = 0; e < 8; ++e) {
                        const int col = kk + e;
                        pu[r][e] = col < g.klim ? ap[col] : 0.f;
                    }
                }
            } else if constexpr (AMODE == AM_ALT) {
                const float* ep = g.enc + ar[r] * 512 + kk;
                const float* mp = g.km + (ar[r] >> 4) * 512 + kk;
                pe[r][0] = *(const f32x4*)ep;
                pe[r][1] = *(const f32x4*)(ep + 4);
                pq[r][0] = *(const f32x4*)mp;
                pq[r][1] = *(const f32x4*)(mp + 4);
                px[r] = *(const bf16x8*)(g.key1 + ar[r] * 512 + kk);
            }
        }
    };

    auto writeA = [&]() {
#pragma unroll
        for (int r = 0; r < 4; ++r) {
            bf16x8 t;
            if constexpr (AMODE == AM_F32) {
#pragma unroll
                for (int e = 0; e < 4; ++e) {
                    t[e]     = (bf16)pf[r][0][e];
                    t[e + 4] = (bf16)pf[r][1][e];
                }
            } else if constexpr (AMODE == AM_F32U) {
#pragma unroll
                for (int e = 0; e < 8; ++e) t[e] = (bf16)pu[r][e];
            } else {  // AM_ALT: enc + km[row/16] - key1/16
#pragma unroll
                for (int e = 0; e < 4; ++e) {
                    t[e]     = (bf16)(pe[r][0][e] + pq[r][0][e] - (float)px[r][e] * 0.0625f);
                    t[e + 4] = (bf16)(pe[r][1][e] + pq[r][1][e] - (float)px[r][e + 4] * 0.0625f);
                }
            }
            *(bf16x8*)(&As[cm[r] * 64 + cs[r] * 8]) = t;
        }
    };

    if constexpr (AMODE != AM_BF16) loadA(0);

    for (int ks = 0; ks < g.nK; ++ks) {
        const int k0 = ks * 64;
        __syncthreads();

        // ---- stage A (128 rows x 64 cols = 1024 16B chunks) ----
        if constexpr (AMODE == AM_BF16) {
            const int cbase = wave * 256;
#pragma unroll
            for (int r = 0; r < 4; ++r) {
                const int c = cbase + r * 64 + lane;
                const int m = c >> 3, s = c & 7;
                const int pg = (s - m) & 7;
                gl_lds16(g.Ab + (m0 + m) * g.lda + k0 + pg * 8, &As[c * 8]);
            }
        } else {
            writeA();
        }

        // ---- stage B ----
        {
            const int cbase = wave * 256;
#pragma unroll
            for (int r = 0; r < 4; ++r) {
                const int c = cbase + r * 64 + lane;
                const int n = c >> 3, s = c & 7;
                const int pg = (s - n) & 7;
                gl_lds16(g.W + (n0 + n) * g.ldw + k0 + pg * 8, &Bs[c * 8]);
            }
        }
        __syncthreads();

        // issue next K-step's A-source loads; latency hides under the MFMAs
        if constexpr (AMODE != AM_BF16) {
            if (ks + 1 < g.nK) loadA(k0 + 64);
        }

        // ---- compute: 2 k-subs x 16 MFMA ----
#pragma unroll
        for (int ksub = 0; ksub < 2; ++ksub) {
            bf16x8 av[4], bv[4];
#pragma unroll
            for (int t = 0; t < 4; ++t) {
                const int m = wm + t * 16 + ln;
                const int sa = ((ksub * 4 + quad) + m) & 7;
                av[t] = *(const bf16x8*)(&As[m * 64 + sa * 8]);
                const int n = wn + t * 16 + ln;
                const int sb = ((ksub * 4 + quad) + n) & 7;
                bv[t] = *(const bf16x8*)(&Bs[n * 64 + sb * 8]);
            }
#pragma unroll
            for (int i = 0; i < 4; ++i)
#pragma unroll
                for (int j = 0; j < 4; ++j)
                    acc[i][j] = __builtin_amdgcn_mfma_f32_16x16x32_bf16(
                        av[i], bv[j], acc[i][j], 0, 0, 0);
        }
    }

    // ---- epilogue ----
#pragma unroll
    for (int i = 0; i < 4; ++i) {
        const long rb = m0 + wm + i * 16 + quad * 4;
#pragma unroll
        for (int j = 0; j < 4; ++j) {
            const long n = n0 + wn + j * 16 + ln;
            const float bvs = g.bias[n];
#pragma unroll
            for (int r = 0; r < 4; ++r) {
                float v = acc[i][j][r] + bvs;
                if constexpr (ACT >= ACT_ELU) v = elu1(v);
                if constexpr (ACT == ACT_ELU2) v = elu1(v);
                const long o = (rb + r) * g.ldc + n;
                if constexpr (OUTB) g.Cb[o] = (bf16)v;
                else                g.Cf[o] = v;
            }
        }
    }
}

// ---------------------------------------------------------------------------
// Per-group attention: one wave per (group, head). Computes
// obar[g] = mean_i softmax_j(q_i.k_j/16) @ V  directly (mean folded in).
// ---------------------------------------------------------------------------
__global__ __launch_bounds__(256) void attn_k(const bf16* __restrict__ qkv,
                                              bf16* __restrict__ obar,
                                              int ngroups) {
    const int tid = blockIdx.x * 256 + threadIdx.x;
    const int wv = tid >> 6;
    const int g  = wv >> 1;
    const int h  = wv & 1;
    if (g >= ngroups) return;
    const int lane = threadIdx.x & 63;
    const int i  = lane & 15;
    const int jb = (lane >> 4) << 2;

    const bf16* base  = qkv + (long)g * 16 * 1536;
    const bf16* qrow  = base + (long)i * 1536 + h * 256;
    const bf16* kbase = base + 512 + h * 256;

    float s0 = 0.f, s1 = 0.f, s2 = 0.f, s3 = 0.f;
    for (int kk = 0; kk < 256; kk += 8) {
        bf16x8 qv = *(const bf16x8*)(qrow + kk);
        float qf[8];
#pragma unroll
        for (int e = 0; e < 8; ++e) qf[e] = (float)qv[e];
        bf16x8 k0 = *(const bf16x8*)(kbase + (long)(jb + 0) * 1536 + kk);
        bf16x8 k1 = *(const bf16x8*)(kbase + (long)(jb + 1) * 1536 + kk);
        bf16x8 k2 = *(const bf16x8*)(kbase + (long)(jb + 2) * 1536 + kk);
        bf16x8 k3 = *(const bf16x8*)(kbase + (long)(jb + 3) * 1536 + kk);
#pragma unroll
        for (int e = 0; e < 8; ++e) {
            s0 += qf[e] * (float)k0[e];
            s1 += qf[e] * (float)k1[e];
            s2 += qf[e] * (float)k2[e];
            s3 += qf[e] * (float)k3[e];
        }
    }
    const float sc = 1.f / 16.f;  // 1/sqrt(dh), dh=256
    s0 *= sc; s1 *= sc; s2 *= sc; s3 *= sc;
    float m = fmaxf(fmaxf(s0, s1), fmaxf(s2, s3));
    m = fmaxf(m, __shfl_xor(m, 16));
    m = fmaxf(m, __shfl_xor(m, 32));
    float e0 = __expf(s0 - m), e1 = __expf(s1 - m), e2 = __expf(s2 - m), e3 = __expf(s3 - m);
    float rs = e0 + e1 + e2 + e3;
    rs += __shfl_xor(rs, 16);
    rs += __shfl_xor(rs, 32);
    const float inv = 1.f / (rs * 16.f);  // row-normalize + mean over i
    float cb[4] = {e0 * inv, e1 * inv, e2 * inv, e3 * inv};
#pragma unroll
    for (int msk = 1; msk <= 8; msk <<= 1) {
        cb[0] += __shfl_xor(cb[0], msk);
        cb[1] += __shfl_xor(cb[1], msk);
        cb[2] += __shfl_xor(cb[2], msk);
        cb[3] += __shfl_xor(cb[3], msk);
    }
    float call[16];
#pragma unroll
    for (int j = 0; j < 16; ++j)
        call[j] = __shfl(cb[j & 3], (j >> 2) << 4);

    const int d0 = lane << 2;
    const bf16* vb = base + 1024 + h * 256 + d0;
    float o0 = 0.f, o1 = 0.f, o2 = 0.f, o3 = 0.f;
#pragma unroll
    for (int j = 0; j < 16; ++j) {
        bf16x4 vv = *(const bf16x4*)(vb + (long)j * 1536);
        o0 += call[j] * (float)vv[0];
        o1 += call[j] * (float)vv[1];
        o2 += call[j] * (float)vv[2];
        o3 += call[j] * (float)vv[3];
    }
    bf16x4 ov;
    ov[0] = (bf16)o0; ov[1] = (bf16)o1; ov[2] = (bf16)o2; ov[3] = (bf16)o3;
    *(bf16x4*)(obar + (long)g * 512 + h * 256 + d0) = ov;
}

// q_jt = hg3 @ g_w4^T + g_b4  (4096 x 1)
__global__ void qjt_k(const bf16* __restrict__ hg, const bf16* __restrict__ w,
                      const float* __restrict__ b, float* __restrict__ out) {
    const int m = blockIdx.x * 256 + threadIdx.x;
    const bf16* hp = hg + (long)m * 256;
    float acc = 0.f;
    for (int k = 0; k < 256; k += 8) {
        bf16x8 hv = *(const bf16x8*)(hp + k);
        bf16x8 wv = *(const bf16x8*)(w + k);
#pragma unroll
        for (int e = 0; e < 8; ++e) acc += (float)hv[e] * (float)wv[e];
    }
    out[m] = acc + b[0];
}

// alt_q = hp2 @ phi2_w3^T + phi2_b3  (65536 x 2)
__global__ void altq_k(const bf16* __restrict__ hp, const bf16* __restrict__ w,
                       const float* __restrict__ b, float* __restrict__ out) {
    const int m = blockIdx.x * 256 + threadIdx.x;
    const bf16* hr = hp + (long)m * 256;
    float a0 = 0.f, a1 = 0.f;
    for (int k = 0; k < 256; k += 8) {
        bf16x8 hv = *(const bf16x8*)(hr + k);
        bf16x8 w0 = *(const bf16x8*)(w + k);
        bf16x8 w1 = *(const bf16x8*)(w + 256 + k);
#pragma unroll
        for (int e = 0; e < 8; ++e) {
            float hf = (float)hv[e];
            a0 += hf * (float)w0[e];
            a1 += hf * (float)w1[e];
        }
    }
    out[2 * m]     = a0 + b[0];
    out[2 * m + 1] = a1 + b[1];
}

// ---------------------------------------------------------------------------
extern "C" void kernel_launch(void* const* d_in, const int* in_sizes, int n_in,
                              void* d_out, int out_size, void* d_ws, size_t ws_size,
                              hipStream_t stream) {
    const float* enc    = (const float*)d_in[0];
    const float* encA   = (const float*)d_in[1];
    const float* w_ain  = (const float*)d_in[2];
    const float* b_ain  = (const float*)d_in[3];
    const float* w_aout = (const float*)d_in[4];
    const float* b_aout = (const float*)d_in[5];
    const float* w_p11  = (const float*)d_in[6];
    const float* b_p11  = (const float*)d_in[7];
    const float* w_p12  = (const float*)d_in[8];
    const float* b_p12  = (const float*)d_in[9];
    const float* w_p13  = (const float*)d_in[10];
    const float* b_p13  = (const float*)d_in[11];
    const float* w_p14  = (const float*)d_in[12];
    const float* b_p14  = (const float*)d_in[13];
    const float* w_g1   = (const float*)d_in[14];
    const float* b_g1   = (const float*)d_in[15];
    const float* w_g2   = (const float*)d_in[16];
    const float* b_g2   = (const float*)d_in[17];
    const float* w_g3   = (const float*)d_in[18];
    const float* b_g3   = (const float*)d_in[19];
    const float* w_g4   = (const float*)d_in[20];
    const float* b_g4   = (const float*)d_in[21];
    const float* w_p21  = (const float*)d_in[22];
    const float* b_p21  = (const float*)d_in[23];
    const float* w_p22  = (const float*)d_in[24];
    const float* b_p22  = (const float*)d_in[25];
    const float* w_p23  = (const float*)d_in[26];
    const float* b_p23  = (const float*)d_in[27];
    float* out = (float*)d_out;

    // ---- workspace layout ----
    char* wsc = (char*)d_ws;
    size_t off = 0;
    auto take = [&](size_t bytes) -> char* {
        char* p = wsc + off;
        off += (bytes + 255) & ~(size_t)255;
        return p;
    };

    // weight bf16 region (contiguous, cvt order); p11 padded 514->576
    const long o_ain  = 0;
    const long o_aout = o_ain + 1536L * 512;
    const long o_p11  = o_aout + 512L * 512;
    const long o_p12  = o_p11 + 256L * 576;
    const long o_p13  = o_p12 + 256L * 256;
    const long o_p14  = o_p13 + 256L * 256;
    const long o_g1   = o_p14 + 512L * 256;
    const long o_g2   = o_g1 + 256L * 512;
    const long o_g3   = o_g2 + 256L * 256;
    const long o_g4   = o_g3 + 256L * 256;
    const long o_p21  = o_g4 + 256L;
    const long o_p22  = o_p21 + 256L * 512;
    const long o_p23  = o_p22 + 256L * 256;
    const long wtot   = o_p23 + 2L * 256;

    bf16*  wb  = (bf16*)take((size_t)wtot * 2);
    bf16*  Ha  = (bf16*)take(65536ull * 256 * 2);
    bf16*  Hb  = (bf16*)take(65536ull * 256 * 2);
    bf16*  K1  = (bf16*)take(65536ull * 512 * 2);
    bf16*  OB  = (bf16*)take(4096ull * 512 * 2);
    float* KM  = (float*)take(4096ull * 512 * 4);
    bf16*  HGa = (bf16*)take(4096ull * 256 * 2);
    bf16*  HGb = (bf16*)take(4096ull * 256 * 2);

    // ---- union region: Apad (phi1-1 bf16 A) aliases the QKV chunk buffer
    // (Apad is dead before the first QKV gemm runs) ----
    const size_t apad_b = 65536ull * 576 * 2;
    const size_t avail = ws_size > off ? ws_size - off : 0;
    bool apad_ok = apad_b <= avail;
    auto qkvb = [](int ch) { return (size_t)(65536 / ch) * 1536 * 2; };
    auto need = [&](size_t q) {
        const size_t a = apad_ok ? apad_b : 0;
        return q > a ? q : a;
    };
    int CH = 16;
    if (need(qkvb(1)) <= avail)      CH = 1;   // full-size QKV if ws permits
    else if (need(qkvb(2)) <= avail) CH = 2;
    else if (need(qkvb(4)) <= avail) CH = 4;
    else if (need(qkvb(8)) <= avail) CH = 8;
    else {
        CH = 16;
        if (need(qkvb(16)) > avail) apad_ok = false;
    }
    bf16* U = (bf16*)take(need(qkvb(CH)));
    bf16* Apad = U;
    bf16* QKV  = U;

    // ---- 1. convert weights (+ encA if workspace permits) ----
    CvtArgs ca;
    const float* srcs[13] = {w_ain, w_aout, w_p11, w_p12, w_p13, w_p14,
                             w_g1, w_g2, w_g3, w_g4, w_p21, w_p22, w_p23};
    const int rows_[13]  = {1536, 512, 256, 256, 256, 512, 256, 256, 256, 1, 256, 256, 2};
    const int scols_[13] = {512, 512, 514, 256, 256, 256, 512, 256, 256, 256, 512, 256, 256};
    const int dcols_[13] = {512, 512, 576, 256, 256, 256, 512, 256, 256, 256, 512, 256, 256};
    for (int s = 0; s < 13; ++s) {
        ca.src[s] = srcs[s]; ca.rows[s] = rows_[s];
        ca.scols[s] = scols_[s]; ca.dcols[s] = dcols_[s];
    }
    ca.total = (int)wtot;
    cvt_k<<<dim3((unsigned)((wtot + 255) / 256)), dim3(256), 0, stream>>>(ca, wb);
    if (apad_ok)
        cvtA_k<<<dim3(18432), dim3(256), 0, stream>>>(encA, Apad);

    GemmArgs ga;

    // ---- 2. phi1 chain ----
    if (apad_ok) {
        ga = {}; ga.Ab = Apad; ga.lda = 576;
        ga.W = wb + o_p11; ga.ldw = 576; ga.bias = b_p11;
        ga.Cb = Ha; ga.ldc = 256; ga.nK = 9;
        gemm_t<AM_BF16, ACT_ELU, true, 3><<<dim3(512, 2), 256, 0, stream>>>(ga);
    } else {
        ga = {}; ga.Af = encA; ga.lda = 514; ga.klim = 514;
        ga.W = wb + o_p11; ga.ldw = 576; ga.bias = b_p11;
        ga.Cb = Ha; ga.ldc = 256; ga.nK = 9;
        gemm_t<AM_F32U, ACT_ELU, true, 2><<<dim3(512, 2), 256, 0, stream>>>(ga);
    }

    ga = {}; ga.Ab = Ha; ga.lda = 256; ga.W = wb + o_p12; ga.ldw = 256;
    ga.bias = b_p12; ga.Cb = Hb; ga.ldc = 256; ga.nK = 4;
    gemm_t<AM_BF16, ACT_ELU2, true, 3><<<dim3(512, 2), 256, 0, stream>>>(ga);

    ga = {}; ga.Ab = Hb; ga.lda = 256; ga.W = wb + o_p13; ga.ldw = 256;
    ga.bias = b_p13; ga.Cb = Ha; ga.ldc = 256; ga.nK = 4;
    gemm_t<AM_BF16, ACT_ELU, true, 3><<<dim3(512, 2), 256, 0, stream>>>(ga);

    ga = {}; ga.Ab = Ha; ga.lda = 256; ga.W = wb + o_p14; ga.ldw = 256;
    ga.bias = b_p14; ga.Cb = K1; ga.ldc = 512; ga.nK = 4;
    gemm_t<AM_BF16, ACT_NONE, true, 3><<<dim3(512, 4), 256, 0, stream>>>(ga);

    // ---- 3. chunked qkv + attention ----
    const int Mc = 65536 / CH;
    const int gc = 4096 / CH;
    for (int c = 0; c < CH; ++c) {
        ga = {}; ga.Ab = K1 + (long)c * Mc * 512; ga.lda = 512;
        ga.W = wb + o_ain; ga.ldw = 512; ga.bias = b_ain;
        ga.Cb = QKV; ga.ldc = 1536; ga.nK = 8;
        gemm_t<AM_BF16, ACT_NONE, true, 3>
            <<<dim3(Mc / 128, 12), 256, 0, stream>>>(ga);
        attn_k<<<dim3((gc * 2) / 4), 256, 0, stream>>>(QKV, OB + (long)c * gc * 512, gc);
    }

    // ---- 4. key1_mean = obar @ attn_out_w^T + b (f32 out) ----
    ga = {}; ga.Ab = OB; ga.lda = 512; ga.W = wb + o_aout; ga.ldw = 512;
    ga.bias = b_aout; ga.Cf = KM; ga.ldc = 512; ga.nK = 8;
    gemm_t<AM_BF16, ACT_NONE, false, 3><<<dim3(32, 4), 256, 0, stream>>>(ga);

    // ---- 5. g head ----
    ga = {}; ga.Af = KM; ga.lda = 512; ga.W = wb + o_g1; ga.ldw = 512;
    ga.bias = b_g1; ga.Cb = HGa; ga.ldc = 256; ga.nK = 8;
    gemm_t<AM_F32, ACT_ELU, true, 2><<<dim3(32, 2), 256, 0, stream>>>(ga);

    ga = {}; ga.Ab = HGa; ga.lda = 256; ga.W = wb + o_g2; ga.ldw = 256;
    ga.bias = b_g2; ga.Cb = HGb; ga.ldc = 256; ga.nK = 4;
    gemm_t<AM_BF16, ACT_ELU, true, 3><<<dim3(32, 2), 256, 0, stream>>>(ga);

    ga = {}; ga.Ab = HGb; ga.lda = 256; ga.W = wb + o_g3; ga.ldw = 256;
    ga.bias = b_g3; ga.Cb = HGa; ga.ldc = 256; ga.nK = 4;
    gemm_t<AM_BF16, ACT_ELU, true, 3><<<dim3(32, 2), 256, 0, stream>>>(ga);

    qjt_k<<<dim3(16), 256, 0, stream>>>(HGa, wb + o_g4, b_g4, out);

    // ---- 6. phi2 chain (alt_val fused into A staging) ----
    ga = {}; ga.enc = enc; ga.km = KM; ga.key1 = K1;
    ga.W = wb + o_p21; ga.ldw = 512; ga.bias = b_p21;
    ga.Cb = Ha; ga.ldc = 256; ga.nK = 8;
    gemm_t<AM_ALT, ACT_ELU, true, 2><<<dim3(512, 2), 256, 0, stream>>>(ga);

    ga = {}; ga.Ab = Ha; ga.lda = 256; ga.W = wb + o_p22; ga.ldw = 256;
    ga.bias = b_p22; ga.Cb = Hb; ga.ldc = 256; ga.nK = 4;
    gemm_t<AM_BF16, ACT_ELU, true, 3><<<dim3(512, 2), 256, 0, stream>>>(ga);

    altq_k<<<dim3(256), 256, 0, stream>>>(Hb, wb + o_p23, b_p23, out + 4096);
}

// Round 6
// 760.981 us; speedup vs baseline: 1.3485x; 1.0465x over previous
//
#include <hip/hip_runtime.h>
#include <cstdint>

typedef __bf16 bf16;
typedef __attribute__((ext_vector_type(8))) __bf16 bf16x8;
typedef __attribute__((ext_vector_type(4))) __bf16 bf16x4;
typedef __attribute__((ext_vector_type(4))) float f32x4;
typedef __attribute__((ext_vector_type(2))) float f32x2;

static __device__ __forceinline__ float elu1(float x) {
    return x > 0.f ? x : (__expf(x) - 1.f);
}

// global -> LDS async copy, 16 B per lane. LDS dest must be wave-uniform
// base + lane*16 (pass per-lane ptr; lane 0's value is the base).
static __device__ __forceinline__ void gl_lds16(const void* gp, void* lp) {
    __builtin_amdgcn_global_load_lds(
        (const __attribute__((address_space(1))) void*)(uintptr_t)gp,
        (__attribute__((address_space(3))) void*)(uint32_t)(uintptr_t)lp,
        16, 0, 0);
}

// ---------------------------------------------------------------------------
// Weight conversion: f32 -> bf16, all weights concatenated into ws, with
// phi1_w1 row-padded 514 -> 576 (zeros) so K-steps stay 64-wide.
// ---------------------------------------------------------------------------
struct CvtArgs {
    const float* src[13];
    int rows[13];
    int scols[13];
    int dcols[13];
    int total;
};

__global__ void cvt_k(CvtArgs a, bf16* __restrict__ dst) {
    int idx = blockIdx.x * 256 + threadIdx.x;
    if (idx >= a.total) return;
    int rem = idx;
#pragma unroll 1
    for (int s = 0; s < 13; ++s) {
        int sz = a.rows[s] * a.dcols[s];
        if (rem < sz) {
            int r = rem / a.dcols[s];
            int c = rem - r * a.dcols[s];
            float v = (c < a.scols[s]) ? a.src[s][(long)r * a.scols[s] + c] : 0.f;
            dst[idx] = (bf16)v;
            return;
        }
        rem -= sz;
    }
}

// encA (65536 x 514 f32) -> Apad (65536 x 576 bf16, zero-padded).
// One 8-col chunk per thread, vectorized f32x2 loads (rows are 8B-aligned).
__global__ void cvtA_k(const float* __restrict__ src, bf16* __restrict__ dst) {
    const int idx = blockIdx.x * 256 + threadIdx.x;
    const int r = idx / 72;            // 72 = 576/8 chunks per row
    const int c8 = (idx - r * 72) * 8;
    const float* sp = src + (long)r * 514 + c8;
    bf16x8 t;
    if (c8 + 8 <= 514) {
        f32x2 p0 = *(const f32x2*)(sp + 0);
        f32x2 p1 = *(const f32x2*)(sp + 2);
        f32x2 p2 = *(const f32x2*)(sp + 4);
        f32x2 p3 = *(const f32x2*)(sp + 6);
        t[0] = (bf16)p0.x; t[1] = (bf16)p0.y; t[2] = (bf16)p1.x; t[3] = (bf16)p1.y;
        t[4] = (bf16)p2.x; t[5] = (bf16)p2.y; t[6] = (bf16)p3.x; t[7] = (bf16)p3.y;
    } else {
#pragma unroll
        for (int e = 0; e < 8; ++e) {
            const int col = c8 + e;
            t[e] = (bf16)(col < 514 ? sp[e] : 0.f);
        }
    }
    *(bf16x8*)(dst + (long)r * 576 + c8) = t;
}

// ---------------------------------------------------------------------------
// Tiled GEMM (m97 structure): C = act(A @ W^T + bias)
// 128x128 block tile, BK=64, 256 threads = 4 waves, each wave 64x64
// (4x4 grid of 16x16x32 MFMA). LDS staged via global_load_lds (bf16
// operands) or VALU compose + ds_write (f32 / fused alt_val A).
// Single-buffer 2-phase loop (sync, stage, sync, compute) — measured
// fastest; both double-buffer variants regressed (r2/r3), WPE>2 caps
// VGPRs and is neutral-to-harmful (r4/r5). Keep __launch_bounds__(256,2).
// A-panel L2-reuse swizzle (r5 diagnosis: QKV FETCH = 5x ideal because
// the gy blocks sharing an A-panel run ~gridX dispatches apart): decode
// (bx,by) from the linear dispatch id so panel-sharers are spaced exactly
// 8 apart -> same XCD under round-robin assignment, co-resident in time
// -> one L2 fetch per panel per sweep. Supergroup = 8 panels x gy.
// Non-bf16 A modes register-prefetch the next K-step's raw A sources
// after the second barrier so their HBM latency hides under the MFMAs.
// Swizzled LDS layout: 16B chunk p of row m stored at slot (p+m)&7.
// ---------------------------------------------------------------------------
struct GemmArgs {
    const float* Af;
    const bf16*  Ab;
    long lda;
    const float* enc;    // ALT mode
    const float* km;     // ALT mode
    const bf16*  key1;   // ALT mode
    const bf16*  W;
    long ldw;
    const float* bias;
    bf16*  Cb;
    float* Cf;
    long ldc;
    int nK;              // number of 64-wide K-steps
    int klim;            // valid A cols (F32U bounds)
};

enum { AM_F32 = 0, AM_F32U = 1, AM_BF16 = 2, AM_ALT = 3 };
enum { ACT_NONE = 0, ACT_ELU = 1, ACT_ELU2 = 2 };

template <int AMODE, int ACT, bool OUTB>
__global__ __launch_bounds__(256, 2) void gemm_t(GemmArgs g) {
    __shared__ bf16 As[128 * 64];
    __shared__ bf16 Bs[128 * 64];

    const int tid  = threadIdx.x;
    const int wave = tid >> 6;
    const int lane = tid & 63;
    const int ln   = lane & 15;
    const int quad = lane >> 4;

    // ---- A-panel-sharing block swizzle ----
    int bx, by;
    {
        const int gx = gridDim.x;
        const int gy = gridDim.y;
        const int cid = blockIdx.x + blockIdx.y * gx;
        const int sgsz = 8 * gy;               // blocks per supergroup
        const int nfull = gx >> 3;             // full supergroups
        const int sgi = cid / sgsz;
        const int r = cid - sgi * sgsz;
        if (sgi < nfull) {
            bx = (sgi << 3) + (r & 7);         // panel-sharers spaced 8 apart
            by = r >> 3;
        } else {                               // gx % 8 != 0 tail (unused here)
            int rem = gx - (nfull << 3);
            if (rem == 0) rem = 8;
            bx = (nfull << 3) + (r % rem);
            by = r / rem;
        }
    }
    const long m0 = (long)bx * 128;
    const long n0 = (long)by * 128;
    const int  wm = (wave & 1) * 64;
    const int  wn = (wave >> 1) * 64;

    f32x4 acc[4][4] = {};

    // per-thread A-chunk metadata for VALU-composed modes (loop-invariant)
    int cm[4], cs[4];
    long ar[4];
    if constexpr (AMODE != AM_BF16) {
#pragma unroll
        for (int r = 0; r < 4; ++r) {
            const int c = r * 256 + tid;
            cm[r] = c >> 3;
            cs[r] = c & 7;
            ar[r] = m0 + cm[r];
        }
    }

    // prefetch registers (only the set for the active mode is live)
    f32x4 pf[4][2];                     // AM_F32
    float pu[4][8];                     // AM_F32U
    f32x4 pe[4][2], pq[4][2];           // AM_ALT
    bf16x8 px[4];                       // AM_ALT

    auto loadA = [&](int k0) {
#pragma unroll
        for (int r = 0; r < 4; ++r) {
            const int kk = k0 + (((cs[r] - cm[r]) & 7) << 3);
            if constexpr (AMODE == AM_F32) {
                const float* ap = g.Af + ar[r] * g.lda + kk;
                pf[r][0] = *(const f32x4*)ap;
                pf[r][1] = *(const f32x4*)(ap + 4);
            } else if constexpr (AMODE == AM_F32U) {
                const float* ap = g.Af + ar[r] * g.lda;
                if (kk + 8 <= g.klim) {
#pragma unroll
                    for (int e = 0; e < 8; e += 2) {
                        f32x2 p = *(const f32x2*)(ap + kk + e);
                        pu[r][e] = p.x;
                        pu[r][e + 1] = p.y;
                    }
                } else {
#pragma unroll
                    for (int e = 0; e < 8; ++e) {
                        const int col = kk + e;
                        pu[r][e] = col < g.klim ? ap[col] : 0.f;
                    }
                }
            } else if constexpr (AMODE == AM_ALT) {
                const float* ep = g.enc + ar[r] * 512 + kk;
                const float* mp = g.km + (ar[r] >> 4) * 512 + kk;
                pe[r][0] = *(const f32x4*)ep;
                pe[r][1] = *(const f32x4*)(ep + 4);
                pq[r][0] = *(const f32x4*)mp;
                pq[r][1] = *(const f32x4*)(mp + 4);
                px[r] = *(const bf16x8*)(g.key1 + ar[r] * 512 + kk);
            }
        }
    };

    auto writeA = [&]() {
#pragma unroll
        for (int r = 0; r < 4; ++r) {
            bf16x8 t;
            if constexpr (AMODE == AM_F32) {
#pragma unroll
                for (int e = 0; e < 4; ++e) {
                    t[e]     = (bf16)pf[r][0][e];
                    t[e + 4] = (bf16)pf[r][1][e];
                }
            } else if constexpr (AMODE == AM_F32U) {
#pragma unroll
                for (int e = 0; e < 8; ++e) t[e] = (bf16)pu[r][e];
            } else {  // AM_ALT: enc + km[row/16] - key1/16
#pragma unroll
                for (int e = 0; e < 4; ++e) {
                    t[e]     = (bf16)(pe[r][0][e] + pq[r][0][e] - (float)px[r][e] * 0.0625f);
                    t[e + 4] = (bf16)(pe[r][1][e] + pq[r][1][e] - (float)px[r][e + 4] * 0.0625f);
                }
            }
            *(bf16x8*)(&As[cm[r] * 64 + cs[r] * 8]) = t;
        }
    };

    if constexpr (AMODE != AM_BF16) loadA(0);

    for (int ks = 0; ks < g.nK; ++ks) {
        const int k0 = ks * 64;
        __syncthreads();

        // ---- stage A (128 rows x 64 cols = 1024 16B chunks) ----
        if constexpr (AMODE == AM_BF16) {
            const int cbase = wave * 256;
#pragma unroll
            for (int r = 0; r < 4; ++r) {
                const int c = cbase + r * 64 + lane;
                const int m = c >> 3, s = c & 7;
                const int pg = (s - m) & 7;
                gl_lds16(g.Ab + (m0 + m) * g.lda + k0 + pg * 8, &As[c * 8]);
            }
        } else {
            writeA();
        }

        // ---- stage B ----
        {
            const int cbase = wave * 256;
#pragma unroll
            for (int r = 0; r < 4; ++r) {
                const int c = cbase + r * 64 + lane;
                const int n = c >> 3, s = c & 7;
                const int pg = (s - n) & 7;
                gl_lds16(g.W + (n0 + n) * g.ldw + k0 + pg * 8, &Bs[c * 8]);
            }
        }
        __syncthreads();

        // issue next K-step's A-source loads; latency hides under the MFMAs
        if constexpr (AMODE != AM_BF16) {
            if (ks + 1 < g.nK) loadA(k0 + 64);
        }

        // ---- compute: 2 k-subs x 16 MFMA ----
#pragma unroll
        for (int ksub = 0; ksub < 2; ++ksub) {
            bf16x8 av[4], bv[4];
#pragma unroll
            for (int t = 0; t < 4; ++t) {
                const int m = wm + t * 16 + ln;
                const int sa = ((ksub * 4 + quad) + m) & 7;
                av[t] = *(const bf16x8*)(&As[m * 64 + sa * 8]);
                const int n = wn + t * 16 + ln;
                const int sb = ((ksub * 4 + quad) + n) & 7;
                bv[t] = *(const bf16x8*)(&Bs[n * 64 + sb * 8]);
            }
#pragma unroll
            for (int i = 0; i < 4; ++i)
#pragma unroll
                for (int j = 0; j < 4; ++j)
                    acc[i][j] = __builtin_amdgcn_mfma_f32_16x16x32_bf16(
                        av[i], bv[j], acc[i][j], 0, 0, 0);
        }
    }

    // ---- epilogue ----
#pragma unroll
    for (int i = 0; i < 4; ++i) {
        const long rb = m0 + wm + i * 16 + quad * 4;
#pragma unroll
        for (int j = 0; j < 4; ++j) {
            const long n = n0 + wn + j * 16 + ln;
            const float bvs = g.bias[n];
#pragma unroll
            for (int r = 0; r < 4; ++r) {
                float v = acc[i][j][r] + bvs;
                if constexpr (ACT >= ACT_ELU) v = elu1(v);
                if constexpr (ACT == ACT_ELU2) v = elu1(v);
                const long o = (rb + r) * g.ldc + n;
                if constexpr (OUTB) g.Cb[o] = (bf16)v;
                else                g.Cf[o] = v;
            }
        }
    }
}

// ---------------------------------------------------------------------------
// Per-group attention: one wave per (group, head). Computes
// obar[g] = mean_i softmax_j(q_i.k_j/16) @ V  directly (mean folded in).
// ---------------------------------------------------------------------------
__global__ __launch_bounds__(256) void attn_k(const bf16* __restrict__ qkv,
                                              bf16* __restrict__ obar,
                                              int ngroups) {
    const int tid = blockIdx.x * 256 + threadIdx.x;
    const int wv = tid >> 6;
    const int g  = wv >> 1;
    const int h  = wv & 1;
    if (g >= ngroups) return;
    const int lane = threadIdx.x & 63;
    const int i  = lane & 15;
    const int jb = (lane >> 4) << 2;

    const bf16* base  = qkv + (long)g * 16 * 1536;
    const bf16* qrow  = base + (long)i * 1536 + h * 256;
    const bf16* kbase = base + 512 + h * 256;

    float s0 = 0.f, s1 = 0.f, s2 = 0.f, s3 = 0.f;
    for (int kk = 0; kk < 256; kk += 8) {
        bf16x8 qv = *(const bf16x8*)(qrow + kk);
        float qf[8];
#pragma unroll
        for (int e = 0; e < 8; ++e) qf[e] = (float)qv[e];
        bf16x8 k0 = *(const bf16x8*)(kbase + (long)(jb + 0) * 1536 + kk);
        bf16x8 k1 = *(const bf16x8*)(kbase + (long)(jb + 1) * 1536 + kk);
        bf16x8 k2 = *(const bf16x8*)(kbase + (long)(jb + 2) * 1536 + kk);
        bf16x8 k3 = *(const bf16x8*)(kbase + (long)(jb + 3) * 1536 + kk);
#pragma unroll
        for (int e = 0; e < 8; ++e) {
            s0 += qf[e] * (float)k0[e];
            s1 += qf[e] * (float)k1[e];
            s2 += qf[e] * (float)k2[e];
            s3 += qf[e] * (float)k3[e];
        }
    }
    const float sc = 1.f / 16.f;  // 1/sqrt(dh), dh=256
    s0 *= sc; s1 *= sc; s2 *= sc; s3 *= sc;
    float m = fmaxf(fmaxf(s0, s1), fmaxf(s2, s3));
    m = fmaxf(m, __shfl_xor(m, 16));
    m = fmaxf(m, __shfl_xor(m, 32));
    float e0 = __expf(s0 - m), e1 = __expf(s1 - m), e2 = __expf(s2 - m), e3 = __expf(s3 - m);
    float rs = e0 + e1 + e2 + e3;
    rs += __shfl_xor(rs, 16);
    rs += __shfl_xor(rs, 32);
    const float inv = 1.f / (rs * 16.f);  // row-normalize + mean over i
    float cb[4] = {e0 * inv, e1 * inv, e2 * inv, e3 * inv};
#pragma unroll
    for (int msk = 1; msk <= 8; msk <<= 1) {
        cb[0] += __shfl_xor(cb[0], msk);
        cb[1] += __shfl_xor(cb[1], msk);
        cb[2] += __shfl_xor(cb[2], msk);
        cb[3] += __shfl_xor(cb[3], msk);
    }
    float call[16];
#pragma unroll
    for (int j = 0; j < 16; ++j)
        call[j] = __shfl(cb[j & 3], (j >> 2) << 4);

    const int d0 = lane << 2;
    const bf16* vb = base + 1024 + h * 256 + d0;
    float o0 = 0.f, o1 = 0.f, o2 = 0.f, o3 = 0.f;
#pragma unroll
    for (int j = 0; j < 16; ++j) {
        bf16x4 vv = *(const bf16x4*)(vb + (long)j * 1536);
        o0 += call[j] * (float)vv[0];
        o1 += call[j] * (float)vv[1];
        o2 += call[j] * (float)vv[2];
        o3 += call[j] * (float)vv[3];
    }
    bf16x4 ov;
    ov[0] = (bf16)o0; ov[1] = (bf16)o1; ov[2] = (bf16)o2; ov[3] = (bf16)o3;
    *(bf16x4*)(obar + (long)g * 512 + h * 256 + d0) = ov;
}

// q_jt = hg3 @ g_w4^T + g_b4  (4096 x 1)
__global__ void qjt_k(const bf16* __restrict__ hg, const bf16* __restrict__ w,
                      const float* __restrict__ b, float* __restrict__ out) {
    const int m = blockIdx.x * 256 + threadIdx.x;
    const bf16* hp = hg + (long)m * 256;
    float acc = 0.f;
    for (int k = 0; k < 256; k += 8) {
        bf16x8 hv = *(const bf16x8*)(hp + k);
        bf16x8 wv = *(const bf16x8*)(w + k);
#pragma unroll
        for (int e = 0; e < 8; ++e) acc += (float)hv[e] * (float)wv[e];
    }
    out[m] = acc + b[0];
}

// alt_q = hp2 @ phi2_w3^T + phi2_b3  (65536 x 2)
__global__ void altq_k(const bf16* __restrict__ hp, const bf16* __restrict__ w,
                       const float* __restrict__ b, float* __restrict__ out) {
    const int m = blockIdx.x * 256 + threadIdx.x;
    const bf16* hr = hp + (long)m * 256;
    float a0 = 0.f, a1 = 0.f;
    for (int k = 0; k < 256; k += 8) {
        bf16x8 hv = *(const bf16x8*)(hr + k);
        bf16x8 w0 = *(const bf16x8*)(w + k);
        bf16x8 w1 = *(const bf16x8*)(w + 256 + k);
#pragma unroll
        for (int e = 0; e < 8; ++e) {
            float hf = (float)hv[e];
            a0 += hf * (float)w0[e];
            a1 += hf * (float)w1[e];
        }
    }
    out[2 * m]     = a0 + b[0];
    out[2 * m + 1] = a1 + b[1];
}

// ---------------------------------------------------------------------------
extern "C" void kernel_launch(void* const* d_in, const int* in_sizes, int n_in,
                              void* d_out, int out_size, void* d_ws, size_t ws_size,
                              hipStream_t stream) {
    const float* enc    = (const float*)d_in[0];
    const float* encA   = (const float*)d_in[1];
    const float* w_ain  = (const float*)d_in[2];
    const float* b_ain  = (const float*)d_in[3];
    const float* w_aout = (const float*)d_in[4];
    const float* b_aout = (const float*)d_in[5];
    const float* w_p11  = (const float*)d_in[6];
    const float* b_p11  = (const float*)d_in[7];
    const float* w_p12  = (const float*)d_in[8];
    const float* b_p12  = (const float*)d_in[9];
    const float* w_p13  = (const float*)d_in[10];
    const float* b_p13  = (const float*)d_in[11];
    const float* w_p14  = (const float*)d_in[12];
    const float* b_p14  = (const float*)d_in[13];
    const float* w_g1   = (const float*)d_in[14];
    const float* b_g1   = (const float*)d_in[15];
    const float* w_g2   = (const float*)d_in[16];
    const float* b_g2   = (const float*)d_in[17];
    const float* w_g3   = (const float*)d_in[18];
    const float* b_g3   = (const float*)d_in[19];
    const float* w_g4   = (const float*)d_in[20];
    const float* b_g4   = (const float*)d_in[21];
    const float* w_p21  = (const float*)d_in[22];
    const float* b_p21  = (const float*)d_in[23];
    const float* w_p22  = (const float*)d_in[24];
    const float* b_p22  = (const float*)d_in[25];
    const float* w_p23  = (const float*)d_in[26];
    const float* b_p23  = (const float*)d_in[27];
    float* out = (float*)d_out;

    // ---- workspace layout ----
    char* wsc = (char*)d_ws;
    size_t off = 0;
    auto take = [&](size_t bytes) -> char* {
        char* p = wsc + off;
        off += (bytes + 255) & ~(size_t)255;
        return p;
    };

    // weight bf16 region (contiguous, cvt order); p11 padded 514->576
    const long o_ain  = 0;
    const long o_aout = o_ain + 1536L * 512;
    const long o_p11  = o_aout + 512L * 512;
    const long o_p12  = o_p11 + 256L * 576;
    const long o_p13  = o_p12 + 256L * 256;
    const long o_p14  = o_p13 + 256L * 256;
    const long o_g1   = o_p14 + 512L * 256;
    const long o_g2   = o_g1 + 256L * 512;
    const long o_g3   = o_g2 + 256L * 256;
    const long o_g4   = o_g3 + 256L * 256;
    const long o_p21  = o_g4 + 256L;
    const long o_p22  = o_p21 + 256L * 512;
    const long o_p23  = o_p22 + 256L * 256;
    const long wtot   = o_p23 + 2L * 256;

    bf16*  wb  = (bf16*)take((size_t)wtot * 2);
    bf16*  Ha  = (bf16*)take(65536ull * 256 * 2);
    bf16*  Hb  = (bf16*)take(65536ull * 256 * 2);
    bf16*  K1  = (bf16*)take(65536ull * 512 * 2);
    bf16*  OB  = (bf16*)take(4096ull * 512 * 2);
    float* KM  = (float*)take(4096ull * 512 * 4);
    bf16*  HGa = (bf16*)take(4096ull * 256 * 2);
    bf16*  HGb = (bf16*)take(4096ull * 256 * 2);

    // ---- union region: Apad (phi1-1 bf16 A) aliases the QKV chunk buffer
    // (Apad is dead before the first QKV gemm runs) ----
    const size_t apad_b = 65536ull * 576 * 2;
    const size_t avail = ws_size > off ? ws_size - off : 0;
    bool apad_ok = apad_b <= avail;
    auto qkvb = [](int ch) { return (size_t)(65536 / ch) * 1536 * 2; };
    auto need = [&](size_t q) {
        const size_t a = apad_ok ? apad_b : 0;
        return q > a ? q : a;
    };
    int CH = 16;
    if (need(qkvb(1)) <= avail)      CH = 1;   // full-size QKV if ws permits
    else if (need(qkvb(2)) <= avail) CH = 2;
    else if (need(qkvb(4)) <= avail) CH = 4;
    else if (need(qkvb(8)) <= avail) CH = 8;
    else {
        CH = 16;
        if (need(qkvb(16)) > avail) apad_ok = false;
    }
    bf16* U = (bf16*)take(need(qkvb(CH)));
    bf16* Apad = U;
    bf16* QKV  = U;

    // ---- 1. convert weights (+ encA if workspace permits) ----
    CvtArgs ca;
    const float* srcs[13] = {w_ain, w_aout, w_p11, w_p12, w_p13, w_p14,
                             w_g1, w_g2, w_g3, w_g4, w_p21, w_p22, w_p23};
    const int rows_[13]  = {1536, 512, 256, 256, 256, 512, 256, 256, 256, 1, 256, 256, 2};
    const int scols_[13] = {512, 512, 514, 256, 256, 256, 512, 256, 256, 256, 512, 256, 256};
    const int dcols_[13] = {512, 512, 576, 256, 256, 256, 512, 256, 256, 256, 512, 256, 256};
    for (int s = 0; s < 13; ++s) {
        ca.src[s] = srcs[s]; ca.rows[s] = rows_[s];
        ca.scols[s] = scols_[s]; ca.dcols[s] = dcols_[s];
    }
    ca.total = (int)wtot;
    cvt_k<<<dim3((unsigned)((wtot + 255) / 256)), dim3(256), 0, stream>>>(ca, wb);
    if (apad_ok)
        cvtA_k<<<dim3(18432), dim3(256), 0, stream>>>(encA, Apad);

    GemmArgs ga;

    // ---- 2. phi1 chain ----
    if (apad_ok) {
        ga = {}; ga.Ab = Apad; ga.lda = 576;
        ga.W = wb + o_p11; ga.ldw = 576; ga.bias = b_p11;
        ga.Cb = Ha; ga.ldc = 256; ga.nK = 9;
        gemm_t<AM_BF16, ACT_ELU, true><<<dim3(512, 2), 256, 0, stream>>>(ga);
    } else {
        ga = {}; ga.Af = encA; ga.lda = 514; ga.klim = 514;
        ga.W = wb + o_p11; ga.ldw = 576; ga.bias = b_p11;
        ga.Cb = Ha; ga.ldc = 256; ga.nK = 9;
        gemm_t<AM_F32U, ACT_ELU, true><<<dim3(512, 2), 256, 0, stream>>>(ga);
    }

    ga = {}; ga.Ab = Ha; ga.lda = 256; ga.W = wb + o_p12; ga.ldw = 256;
    ga.bias = b_p12; ga.Cb = Hb; ga.ldc = 256; ga.nK = 4;
    gemm_t<AM_BF16, ACT_ELU2, true><<<dim3(512, 2), 256, 0, stream>>>(ga);

    ga = {}; ga.Ab = Hb; ga.lda = 256; ga.W = wb + o_p13; ga.ldw = 256;
    ga.bias = b_p13; ga.Cb = Ha; ga.ldc = 256; ga.nK = 4;
    gemm_t<AM_BF16, ACT_ELU, true><<<dim3(512, 2), 256, 0, stream>>>(ga);

    ga = {}; ga.Ab = Ha; ga.lda = 256; ga.W = wb + o_p14; ga.ldw = 256;
    ga.bias = b_p14; ga.Cb = K1; ga.ldc = 512; ga.nK = 4;
    gemm_t<AM_BF16, ACT_NONE, true><<<dim3(512, 4), 256, 0, stream>>>(ga);

    // ---- 3. chunked qkv + attention ----
    const int Mc = 65536 / CH;
    const int gc = 4096 / CH;
    for (int c = 0; c < CH; ++c) {
        ga = {}; ga.Ab = K1 + (long)c * Mc * 512; ga.lda = 512;
        ga.W = wb + o_ain; ga.ldw = 512; ga.bias = b_ain;
        ga.Cb = QKV; ga.ldc = 1536; ga.nK = 8;
        gemm_t<AM_BF16, ACT_NONE, true>
            <<<dim3(Mc / 128, 12), 256, 0, stream>>>(ga);
        attn_k<<<dim3((gc * 2) / 4), 256, 0, stream>>>(QKV, OB + (long)c * gc * 512, gc);
    }

    // ---- 4. key1_mean = obar @ attn_out_w^T + b (f32 out) ----
    ga = {}; ga.Ab = OB; ga.lda = 512; ga.W = wb + o_aout; ga.ldw = 512;
    ga.bias = b_aout; ga.Cf = KM; ga.ldc = 512; ga.nK = 8;
    gemm_t<AM_BF16, ACT_NONE, false><<<dim3(32, 4), 256, 0, stream>>>(ga);

    // ---- 5. g head ----
    ga = {}; ga.Af = KM; ga.lda = 512; ga.W = wb + o_g1; ga.ldw = 512;
    ga.bias = b_g1; ga.Cb = HGa; ga.ldc = 256; ga.nK = 8;
    gemm_t<AM_F32, ACT_ELU, true><<<dim3(32, 2), 256, 0, stream>>>(ga);

    ga = {}; ga.Ab = HGa; ga.lda = 256; ga.W = wb + o_g2; ga.ldw = 256;
    ga.bias = b_g2; ga.Cb = HGb; ga.ldc = 256; ga.nK = 4;
    gemm_t<AM_BF16, ACT_ELU, true><<<dim3(32, 2), 256, 0, stream>>>(ga);

    ga = {}; ga.Ab = HGb; ga.lda = 256; ga.W = wb + o_g3; ga.ldw = 256;
    ga.bias = b_g3; ga.Cb = HGa; ga.ldc = 256; ga.nK = 4;
    gemm_t<AM_BF16, ACT_ELU, true><<<dim3(32, 2), 256, 0, stream>>>(ga);

    qjt_k<<<dim3(16), 256, 0, stream>>>(HGa, wb + o_g4, b_g4, out);

    // ---- 6. phi2 chain (alt_val fused into A staging) ----
    ga = {}; ga.enc = enc; ga.km = KM; ga.key1 = K1;
    ga.W = wb + o_p21; ga.ldw = 512; ga.bias = b_p21;
    ga.Cb = Ha; ga.ldc = 256; ga.nK = 8;
    gemm_t<AM_ALT, ACT_ELU, true><<<dim3(512, 2), 256, 0, stream>>>(ga);

    ga = {}; ga.Ab = Ha; ga.lda = 256; ga.W = wb + o_p22; ga.ldw = 256;
    ga.bias = b_p22; ga.Cb = Hb; ga.ldc = 256; ga.nK = 4;
    gemm_t<AM_BF16, ACT_ELU, true><<<dim3(512, 2), 256, 0, stream>>>(ga);

    altq_k<<<dim3(256), 256, 0, stream>>>(Hb, wb + o_p23, b_p23, out + 4096);
}